// Round 5
// baseline (332.515 us; speedup 1.0000x reference)
//
#include <hip/hip_runtime.h>
#include <hip/hip_bf16.h>

// C[M,N] = A[M,K] @ W[N,K]^T ; M=32768, N=K=2048. fp32 in/out.
// R5: m201-exact 8-phase schedule. 256x256 tile, BK=64, 8 waves (2M x 4N),
// 2 K-tiles per iter, ONE half-tile staged per phase (2 gload_lds/wave),
// vmcnt gate ONLY at end-P4/end-P8 (vmcnt(4): keeps 2 newest B halves in
// flight), double-barrier phase body per the verified template.
// Per-iter stage ledger (iter processes tiles t=2i buf0, t+1 buf1):
//   P1:A0(t+1)->buf1  P2:A1(t+1)->buf1  P3:B0(t+2)->buf0  P4:B1(t+2)->buf0
//   P5:A0(t+2)->buf0  P6:A1(t+2)->buf0  P7:B0(t+3)->buf1  P8:B1(t+3)->buf1
// Free-check: each stage issues after the barrier retiring the half's last read.
// Gate check: end-P4 vmcnt(4) retires A1(t+1)@P2 and older (needed P5+);
//             end-P8 vmcnt(4) retires A1(t+2)@P6 and older (needed next P1+).

typedef __attribute__((ext_vector_type(8))) short bf16x8;
typedef __attribute__((ext_vector_type(4))) float f32x4;

#define M_DIM 32768
#define N_DIM 2048
#define K_DIM 2048
#define BM 256
#define BN 256
#define BK 64
#define NT (K_DIM / BK)              // 32
#define NBN (N_DIM / BN)             // 8
#define NWG ((M_DIM / BM) * NBN)     // 1024

typedef __attribute__((address_space(3))) char lds_char;
typedef __attribute__((address_space(1))) char glb_char;

__device__ __forceinline__ unsigned short f2bf(float f) {
    __bf16 b = (__bf16)f;   // RNE
    return __builtin_bit_cast(unsigned short, b);
}

// ---------------- fp32 -> bf16 convert (memory-bound, grid-stride) ----------
__global__ __launch_bounds__(256)
void cvt_f32_bf16(const float* __restrict__ src, ushort* __restrict__ dst, int n8) {
    const float4* s4 = (const float4*)src;
    int idx = blockIdx.x * blockDim.x + threadIdx.x;
    int stride = gridDim.x * blockDim.x;
    for (int i = idx; i < n8; i += stride) {
        float4 a = s4[2 * (size_t)i];
        float4 b = s4[2 * (size_t)i + 1];
        ushort r[8] = {f2bf(a.x), f2bf(a.y), f2bf(a.z), f2bf(a.w),
                       f2bf(b.x), f2bf(b.y), f2bf(b.z), f2bf(b.w)};
        *reinterpret_cast<uint4*>(dst + 8 * (size_t)i) =
            *reinterpret_cast<const uint4*>(r);
    }
}

// ---------------- 256^2 8-wave 8-phase bf16 GEMM -----------------------------
__global__ __launch_bounds__(512, 2)
void agmm_8phase(const ushort* __restrict__ A, const ushort* __restrict__ W,
                 float* __restrict__ C) {
    // sA[buf]: buf*32768 ; sB[buf]: 65536 + buf*32768 (256r x 64c bf16, 128B rows)
    __shared__ __attribute__((aligned(16))) char sm[131072];

    const int tid  = threadIdx.x;
    const int lane = tid & 63;
    const int w    = tid >> 6;      // 0..7
    const int wm   = w >> 2;        // 0..1 -> 128-row half of A tile
    const int wn   = w & 3;         // 0..3 -> 64-col slice of B tile

    const int bid = blockIdx.x;
    const int swz = (bid & 7) * (NWG / 8) + (bid >> 3);  // bijective (NWG%8==0)
    const int bm  = swz >> 3;            // 0..127
    const int bn  = swz & (NBN - 1);     // 0..7

    // staging source pre-swizzle (linear LDS dest; read applies same XOR)
    const int lsub = lane >> 3;                       // row&7 at dest
    const int scol = ((lane & 7) ^ lsub) << 3;        // pre-swizzled col elems

    const ushort* Abase = A + (size_t)bm * BM * K_DIM + scol;
    const ushort* Wbase = W + (size_t)bn * BN * K_DIM + scol;

    const int lrow = lane & 15;
    const int fxor = (lrow & 7) << 4;
    const int kcb0 = (lane >> 4) << 4;    // 0,16,32,48 byte k-offset

    f32x4 acc[8][4];
#pragma unroll
    for (int m = 0; m < 8; ++m)
#pragma unroll
        for (int n = 0; n < 4; ++n)
            acc[m][n] = (f32x4){0.f, 0.f, 0.f, 0.f};
    bf16x8 bfr[4][2];   // B-frags, loaded at phase Q0, live for the K-tile

#define GLD16(SRC, LOFF)                                                       \
    __builtin_amdgcn_global_load_lds((const glb_char*)(SRC),                   \
                                     (lds_char*)(sm + (LOFF)), 16, 0, 0)
    // stage one A half-tile (128 rows): wave covers rows H*128 + w*16 .. +15
#define STAGE_A(KT, H, BUF) do {                                               \
        const int ra_ = (H) * 128 + (w << 4);                                  \
        GLD16(Abase + (size_t)(ra_ + lsub) * K_DIM + (KT) * BK,                \
              (BUF) * 32768 + ra_ * 128);                                      \
        GLD16(Abase + (size_t)(ra_ + 8 + lsub) * K_DIM + (KT) * BK,            \
              (BUF) * 32768 + (ra_ + 8) * 128);                                \
    } while (0)
#define STAGE_B(KT, H, BUF) do {                                               \
        const int rb_ = (H) * 128 + (w << 4);                                  \
        GLD16(Wbase + (size_t)(rb_ + lsub) * K_DIM + (KT) * BK,                \
              65536 + (BUF) * 32768 + rb_ * 128);                              \
        GLD16(Wbase + (size_t)(rb_ + 8 + lsub) * K_DIM + (KT) * BK,            \
              65536 + (BUF) * 32768 + (rb_ + 8) * 128);                        \
    } while (0)

    // prologue: tile0 -> buf0 (4 halves), B(1) -> buf1 (2 halves). 12 loads.
    STAGE_A(0, 0, 0); STAGE_A(0, 1, 0);
    STAGE_B(0, 0, 0); STAGE_B(0, 1, 0);
    STAGE_B(1, 0, 1); STAGE_B(1, 1, 1);
    asm volatile("s_waitcnt vmcnt(4)" ::: "memory");   // tile0 landed; B(1) in flight
    __builtin_amdgcn_s_barrier();
    __builtin_amdgcn_sched_barrier(0);

    // phase body (verified template): ds_read | stage | bar | lgkm0 | pin |
    //   setprio1 16xMFMA setprio0 | [gate] | bar | pin
#define PHASE(Q, LOADB, GATE_CODE, STAGE_CODE) do {                            \
        bf16x8 af_[2][2];                                                      \
        _Pragma("unroll") for (int m2 = 0; m2 < 2; ++m2)                       \
        _Pragma("unroll") for (int kk = 0; kk < 2; ++kk)                       \
            af_[m2][kk] = *(const bf16x8*)(sm + abase +                        \
                ((Q) * 32 + m2 * 16) * 128 + ((kk * 64 + kcb0) ^ fxor));       \
        if (LOADB) {                                                           \
            _Pragma("unroll") for (int n = 0; n < 4; ++n)                      \
            _Pragma("unroll") for (int kk = 0; kk < 2; ++kk)                   \
                bfr[n][kk] = *(const bf16x8*)(sm + bbase +                     \
                    (n * 16) * 128 + ((kk * 64 + kcb0) ^ fxor));               \
        }                                                                      \
        STAGE_CODE;                                                            \
        __builtin_amdgcn_s_barrier();                                          \
        asm volatile("s_waitcnt lgkmcnt(0)" ::: "memory");                     \
        __builtin_amdgcn_sched_barrier(0);                                     \
        __builtin_amdgcn_s_setprio(1);                                         \
        _Pragma("unroll") for (int m2 = 0; m2 < 2; ++m2)                       \
        _Pragma("unroll") for (int n = 0; n < 4; ++n)                          \
        _Pragma("unroll") for (int kk = 0; kk < 2; ++kk)                       \
            acc[(Q) * 2 + m2][n] = __builtin_amdgcn_mfma_f32_16x16x32_bf16(    \
                af_[m2][kk], bfr[n][kk], acc[(Q) * 2 + m2][n], 0, 0, 0);       \
        __builtin_amdgcn_s_setprio(0);                                         \
        GATE_CODE;                                                             \
        __builtin_amdgcn_s_barrier();                                          \
        __builtin_amdgcn_sched_barrier(0);                                     \
    } while (0)

#define GATE4  asm volatile("s_waitcnt vmcnt(4)" ::: "memory")
#define GATE0  asm volatile("s_waitcnt vmcnt(0)" ::: "memory")
#define NOGATE do {} while (0)

    for (int i = 0; i < NT / 2 - 1; ++i) {       // 15 steady iters
        const int t0 = 2 * i;
        {   // tile t0 in buf0
            const int abase = (wm * 128 + lrow) * 128;
            const int bbase = 65536 + (wn * 64 + lrow) * 128;
            PHASE(0, 1, NOGATE, STAGE_A(t0 + 1, 0, 1));
            PHASE(1, 0, NOGATE, STAGE_A(t0 + 1, 1, 1));
            PHASE(2, 0, NOGATE, STAGE_B(t0 + 2, 0, 0));
            PHASE(3, 0, GATE4,  STAGE_B(t0 + 2, 1, 0));
        }
        {   // tile t0+1 in buf1
            const int abase = 32768 + (wm * 128 + lrow) * 128;
            const int bbase = 65536 + 32768 + (wn * 64 + lrow) * 128;
            PHASE(0, 1, NOGATE, STAGE_A(t0 + 2, 0, 0));
            PHASE(1, 0, NOGATE, STAGE_A(t0 + 2, 1, 0));
            PHASE(2, 0, NOGATE, STAGE_B(t0 + 3, 0, 1));
            PHASE(3, 0, GATE4,  STAGE_B(t0 + 3, 1, 1));
        }
    }
    {   // peel: tiles NT-2 (buf0), NT-1 (buf1)
        {
            const int abase = (wm * 128 + lrow) * 128;
            const int bbase = 65536 + (wn * 64 + lrow) * 128;
            PHASE(0, 1, NOGATE, STAGE_A(NT - 1, 0, 1));
            PHASE(1, 0, NOGATE, STAGE_A(NT - 1, 1, 1));
            PHASE(2, 0, NOGATE, {});
            PHASE(3, 0, GATE0,  {});
        }
        {
            const int abase = 32768 + (wm * 128 + lrow) * 128;
            const int bbase = 65536 + 32768 + (wn * 64 + lrow) * 128;
            PHASE(0, 1, NOGATE, {});
            PHASE(1, 0, NOGATE, {});
            PHASE(2, 0, NOGATE, {});
            PHASE(3, 0, NOGATE, {});
        }
    }
#undef NOGATE
#undef GATE0
#undef GATE4
#undef PHASE
#undef STAGE_B
#undef STAGE_A
#undef GLD16

    // epilogue: C/D layout col=lane&15, row=(lane>>4)*4+reg (R1-R4 validated)
    const size_t crow = (size_t)(bm * BM + wm * 128 + ((lane >> 4) << 2));
    const int    ccol = bn * BN + wn * 64 + (lane & 15);
    float* Cp = C + crow * N_DIM + ccol;
#pragma unroll
    for (int m = 0; m < 8; ++m)
#pragma unroll
        for (int j = 0; j < 4; ++j) {
            float* cr = Cp + (size_t)(m * 16 + j) * N_DIM;
#pragma unroll
            for (int n = 0; n < 4; ++n)
                cr[n * 16] = acc[m][n][j];
        }
}

// ---------------- fused fp32 fallback (ws too small; R1-validated) ----------
__global__ __launch_bounds__(256, 2)
void agmm_fused(const float* __restrict__ A, const float* __restrict__ W,
                float* __restrict__ C) {
    __shared__ __attribute__((aligned(16))) char sA[128 * 64 * 2];
    __shared__ __attribute__((aligned(16))) char sB[128 * 64 * 2];

    const int tid  = threadIdx.x;
    const int lane = tid & 63;
    const int wid  = tid >> 6;
    const int wm   = wid >> 1;
    const int wn   = wid & 1;

    const int nwg = (M_DIM / 128) * (N_DIM / 128);
    const int bid = blockIdx.x;
    const int swz = (bid & 7) * (nwg / 8) + (bid >> 3);
    const int bm  = swz >> 4;
    const int bn  = swz & 15;

    const int srow = tid >> 4;
    const int scol = (tid & 15) << 2;

    const float* Ap = A + (size_t)(bm * 128 + srow) * K_DIM + scol;
    const float* Wp = W + (size_t)(bn * 128 + srow) * K_DIM + scol;
    const int wbase = (srow * 128 + (scol << 1)) ^ ((srow & 7) << 4);

    const int lrow = lane & 15;
    const int lkb  = (lane >> 4) << 3;
    const int fxor = (lrow & 7) << 4;
    const int arow0 = (wm * 64 + lrow) * 128;
    const int brow0 = (wn * 64 + lrow) * 128;

    f32x4 acc[4][4];
#pragma unroll
    for (int m = 0; m < 4; ++m)
#pragma unroll
        for (int n = 0; n < 4; ++n)
            acc[m][n] = (f32x4){0.f, 0.f, 0.f, 0.f};

    float4 areg[8], breg[8];
#pragma unroll
    for (int p = 0; p < 8; ++p) {
        areg[p] = *reinterpret_cast<const float4*>(Ap + (size_t)p * 16 * K_DIM);
        breg[p] = *reinterpret_cast<const float4*>(Wp + (size_t)p * 16 * K_DIM);
    }

    for (int kt = 0; kt < NT; ++kt) {
        __syncthreads();
#pragma unroll
        for (int p = 0; p < 8; ++p) {
            ushort av[4] = {f2bf(areg[p].x), f2bf(areg[p].y),
                            f2bf(areg[p].z), f2bf(areg[p].w)};
            *reinterpret_cast<ushort4*>(sA + (wbase + p * 2048)) =
                *reinterpret_cast<ushort4*>(av);
            ushort bv[4] = {f2bf(breg[p].x), f2bf(breg[p].y),
                            f2bf(breg[p].z), f2bf(breg[p].w)};
            *reinterpret_cast<ushort4*>(sB + (wbase + p * 2048)) =
                *reinterpret_cast<ushort4*>(bv);
        }
        __syncthreads();

        if (kt + 1 < NT) {
            const float* ap = Ap + (size_t)(kt + 1) * BK;
            const float* wp = Wp + (size_t)(kt + 1) * BK;
#pragma unroll
            for (int p = 0; p < 8; ++p) {
                areg[p] = *reinterpret_cast<const float4*>(ap + (size_t)p * 16 * K_DIM);
                breg[p] = *reinterpret_cast<const float4*>(wp + (size_t)p * 16 * K_DIM);
            }
        }

#pragma unroll
        for (int kk = 0; kk < 2; ++kk) {
            const int kcb = (kk * 32 + lkb) * 2;
            bf16x8 af[4], bfv[4];
#pragma unroll
            for (int m = 0; m < 4; ++m)
                af[m] = *reinterpret_cast<const bf16x8*>(
                    sA + ((arow0 + m * 2048 + kcb) ^ fxor));
#pragma unroll
            for (int n = 0; n < 4; ++n)
                bfv[n] = *reinterpret_cast<const bf16x8*>(
                    sB + ((brow0 + n * 2048 + kcb) ^ fxor));
#pragma unroll
            for (int m = 0; m < 4; ++m)
#pragma unroll
                for (int n = 0; n < 4; ++n)
                    acc[m][n] = __builtin_amdgcn_mfma_f32_16x16x32_bf16(
                        af[m], bfv[n], acc[m][n], 0, 0, 0);
        }
    }

    const size_t crow = (size_t)(bm * 128 + wm * 64 + ((lane >> 4) << 2));
    const int    ccol = bn * 128 + wn * 64 + (lane & 15);
    float* Cp = C + crow * N_DIM + ccol;
#pragma unroll
    for (int m = 0; m < 4; ++m)
#pragma unroll
        for (int j = 0; j < 4; ++j) {
            float* cr = Cp + (size_t)(m * 16 + j) * N_DIM;
#pragma unroll
            for (int n = 0; n < 4; ++n)
                cr[n * 16] = acc[m][n][j];
        }
}

extern "C" void kernel_launch(void* const* d_in, const int* in_sizes, int n_in,
                              void* d_out, int out_size, void* d_ws, size_t ws_size,
                              hipStream_t stream) {
    const float* A  = (const float*)d_in[0];   // [8,4096,2048] fp32
    const float* Wt = (const float*)d_in[1];   // [2048,2048] fp32
    float* C = (float*)d_out;                  // [32768,2048] fp32

    const size_t needA = (size_t)M_DIM * K_DIM * 2;
    const size_t needW = (size_t)N_DIM * K_DIM * 2;

    if (ws_size >= needA + needW) {
        ushort* Abf = (ushort*)d_ws;
        ushort* Wbf = (ushort*)((char*)d_ws + needA);
        cvt_f32_bf16<<<dim3(2048), dim3(256), 0, stream>>>(A, Abf, (M_DIM * K_DIM) / 8);
        cvt_f32_bf16<<<dim3(2048), dim3(256), 0, stream>>>(Wt, Wbf, (N_DIM * K_DIM) / 8);
        agmm_8phase<<<dim3(NWG), dim3(512), 0, stream>>>(Abf, Wbf, C);
    } else {
        agmm_fused<<<dim3((M_DIM / 128) * (N_DIM / 128)), dim3(256), 0, stream>>>(A, Wt, C);
    }
}